// Round 4
// baseline (206.638 us; speedup 1.0000x reference)
//
#include <hip/hip_runtime.h>
#include <hip/hip_bf16.h>

typedef unsigned short u16;
typedef __attribute__((ext_vector_type(8))) short short8;
typedef __attribute__((ext_vector_type(4))) float f32x4;

__device__ __forceinline__ u16 f2b(float f) {
  union { float f; unsigned u; } a; a.f = f;
  unsigned r = a.u + 0x7fffu + ((a.u >> 16) & 1u);   // RNE bf16 (finite inputs)
  return (u16)(r >> 16);
}

__device__ __forceinline__ unsigned pkbf16(float lo, float hi) {
  unsigned r;
  asm("v_cvt_pk_bf16_f32 %0, %1, %2" : "=v"(r) : "v"(lo), "v"(hi));
  return r;
}

#define GLD_LDS16(gp, lp) __builtin_amdgcn_global_load_lds( \
    (const __attribute__((address_space(1))) void*)(gp),    \
    (__attribute__((address_space(3))) void*)(lp), 16, 0, 0)

// ---------------- fp32 -> bf16 convert ----------------
// Q-rows of w_qkv pre-scaled by scale*log2e; w_proj K-columns permuted
// i = a*256 + h*32 + c  ->  i' = h*96 + a*32 + c  (matches attn's feat layout).
__global__ __launch_bounds__(256) void cvt3(
    const float* __restrict__ x, const float* __restrict__ wq, const float* __restrict__ wp,
    u16* __restrict__ xb, u16* __restrict__ wqb, u16* __restrict__ wpb)
{
  const int NX = 8192 * 768 / 4, NQ = 2304 * 768 / 4, NP = 768 * 768 / 4;
  int i = blockIdx.x * 256 + threadIdx.x;
  if (i < NX) {
    float4 v = *(const float4*)&x[(size_t)i * 4];
    u16 o[4] = { f2b(v.x), f2b(v.y), f2b(v.z), f2b(v.w) };
    *(uint2*)&xb[(size_t)i * 4] = *(uint2*)o;
  } else if (i < NX + NQ) {
    int j = i - NX;
    float sc = (j < 147456) ? 0.14724447f : 1.0f;   // rows 0..767 (Q) * scale*log2e
    float4 v = *(const float4*)&wq[(size_t)j * 4];
    u16 o[4] = { f2b(v.x * sc), f2b(v.y * sc), f2b(v.z * sc), f2b(v.w * sc) };
    *(uint2*)&wqb[(size_t)j * 4] = *(uint2*)o;
  } else if (i < NX + NQ + NP) {
    int j = i - NX - NQ;
    int oo = (j * 4) / 768, ii = (j * 4) % 768;
    int a = ii >> 8, h = (ii >> 5) & 7, c = ii & 31;
    float4 v = *(const float4*)&wp[(size_t)j * 4];
    u16 o[4] = { f2b(v.x), f2b(v.y), f2b(v.z), f2b(v.w) };
    *(uint2*)&wpb[oo * 768 + h * 96 + a * 32 + c] = *(uint2*)o;
  }
}

// ---------------- 128x128 bf16 GEMM, C = A @ Bt^T (both K-contiguous) ----------------
__global__ __launch_bounds__(256) void gemm_bt(
    const u16* __restrict__ A, const u16* __restrict__ Bt,
    u16* __restrict__ Cb, float* __restrict__ Cf, const float* __restrict__ bias,
    int M, int N, int K)
{
  __shared__ u16 Al[128 * 32];
  __shared__ u16 Bl[128 * 32];
  const int tid = threadIdx.x;
  const int lane = tid & 63, wave = tid >> 6;
  const int wr = wave >> 1, wc = wave & 1;
  const int g = lane >> 4, c16 = lane & 15;
  const int m0 = blockIdx.y * 128, n0 = blockIdx.x * 128;

  f32x4 acc[4][4] = {};

  const int c0 = tid, c1 = tid + 256;
  const int r0 = c0 >> 2, o0 = (c0 & 3) * 8;
  const int r1 = c1 >> 2, o1 = (c1 & 3) * 8;
  const u16* a0 = A + (size_t)(m0 + r0) * K + o0;
  const u16* a1 = A + (size_t)(m0 + r1) * K + o1;
  const u16* b0 = Bt + (size_t)(n0 + r0) * K + o0;
  const u16* b1 = Bt + (size_t)(n0 + r1) * K + o1;

  for (int k0 = 0; k0 < K; k0 += 32) {
    GLD_LDS16(a0 + k0, Al + c0 * 8);
    GLD_LDS16(a1 + k0, Al + c1 * 8);
    GLD_LDS16(b0 + k0, Bl + c0 * 8);
    GLD_LDS16(b1 + k0, Bl + c1 * 8);
    __syncthreads();
    short8 af[4], bfr[4];
#pragma unroll
    for (int m = 0; m < 4; ++m)
      af[m] = *(const short8*)&Al[(wr * 64 + m * 16 + c16) * 32 + g * 8];
#pragma unroll
    for (int n = 0; n < 4; ++n)
      bfr[n] = *(const short8*)&Bl[(wc * 64 + n * 16 + c16) * 32 + g * 8];
#pragma unroll
    for (int m = 0; m < 4; ++m)
#pragma unroll
      for (int n = 0; n < 4; ++n)
        acc[m][n] = __builtin_amdgcn_mfma_f32_16x16x32_bf16(af[m], bfr[n], acc[m][n], 0, 0, 0);
    __syncthreads();
  }

  if (Cb) {
#pragma unroll
    for (int m = 0; m < 4; ++m) {
      const int row = m0 + wr * 64 + m * 16 + g * 4;
#pragma unroll
      for (int n = 0; n < 4; ++n) {
        const int col = n0 + wc * 64 + n * 16 + c16;
#pragma unroll
        for (int j = 0; j < 4; ++j)
          Cb[(size_t)(row + j) * N + col] = f2b(acc[m][n][j]);
      }
    }
  } else {
#pragma unroll
    for (int m = 0; m < 4; ++m) {
      const int row = m0 + wr * 64 + m * 16 + g * 4;
#pragma unroll
      for (int n = 0; n < 4; ++n) {
        const int col = n0 + wc * 64 + n * 16 + c16;
        const float bb = bias[col];
#pragma unroll
        for (int j = 0; j < 4; ++j)
          Cf[(size_t)(row + j) * N + col] = acc[m][n][j] + bb;
      }
    }
  }
}

// ---------------- V transpose (key-permuted): vt[bh][d][n] ----------------
// Within each 32-key chunk, key o=16*np+4*gp+r stored at slot 8*gp+4*np+r so the
// PV B-fragment's instruction-k order matches the in-register P packing.
__global__ __launch_bounds__(256) void vtrans(const u16* __restrict__ qkv, u16* __restrict__ vt)
{
  __shared__ u16 Vtl[96 * 72];
  const int tid = threadIdx.x;
  const int bh = blockIdx.x >> 4, nt = blockIdx.x & 15;
  const int b = bh >> 3, h = bh & 7;
  const int n0 = nt * 64;
  const size_t tb = (size_t)b * 1024;
#pragma unroll
  for (int i = 0; i < 3; ++i) {
    int c = tid + i * 256;
    int key = c / 12, cc = c % 12;
    uint4 v = *(const uint4*)&qkv[(tb + n0 + key) * 2304 + 1536 + h * 96 + cc * 8];
    union { uint4 u; u16 s[8]; } cv; cv.u = v;
#pragma unroll
    for (int j = 0; j < 8; ++j)
      Vtl[(cc * 8 + j) * 72 + key] = cv.s[j];
  }
  __syncthreads();
#pragma unroll
  for (int i = 0; i < 3; ++i) {
    int c = tid + i * 256;
    int d = c >> 3, c2 = c & 7;
    int chunk = c2 >> 2;
    int kA = ((c2 & 1) << 4) | ((c2 & 2) << 1);   // c2&3 = 0,1,2,3 -> 0,16,4,20
    const u16* src = &Vtl[d * 72 + c2 * 8];
    size_t base = ((size_t)bh * 96 + d) * 1024 + n0 + chunk * 32;
    *(uint2*)&vt[base + kA]     = *(const uint2*)(src);
    *(uint2*)&vt[base + kA + 8] = *(const uint2*)(src + 4);
  }
}

// ---------------- tri-attention: 16 q/wave, in-register P, ones-MFMA rowsum ----------------
// 1-D grid 1024: id = h + 8*qt + 128*b -> all q-tiles of one (b,h) on one XCD.
// S^T = mfma(K,Q) (Q pre-scaled by c2s); P = exp2 in-register -> cvt_pk -> PV.
// Row-sum via mfma(pa, ones). (q5,k5) block shared by x4/x5 (att=3).
// Epilogue: per-wave LDS transpose (overlaid on Kl) -> 16B coalesced feat stores
// in the permuted layout col' = h*96 + a*32 + c (w_proj permuted to match).
__global__ __launch_bounds__(256, 2) void attn_kernel(
    const u16* __restrict__ qkv, const u16* __restrict__ vt, u16* __restrict__ feat)
{
  __shared__ u16 smem[3 * 64 * 40 + 96 * 72];   // Kl(3x64x40) | Vl(96x72) = 29184 B
  u16* Kl = smem;                // [ks][key][32d], row stride 40 (+8 pad)
  u16* Vl = smem + 3 * 64 * 40;  // [d][64 key-slots], row stride 72 (+8 pad)

  const int tid = threadIdx.x;
  const int lane = tid & 63, wave = tid >> 6;
  const int g = lane >> 4, c16 = lane & 15;
  const int id = blockIdx.x;
  const int h = id & 7, qt = (id >> 3) & 15, b = id >> 7;
  const int bh = b * 8 + h;
  const int q0 = qt * 64 + wave * 16;
  const size_t tb = (size_t)b * 1024;

  short8 qf[2];
#pragma unroll
  for (int qs = 0; qs < 2; ++qs)
    qf[qs] = *(const short8*)&qkv[(tb + q0 + c16) * 2304 + h * 96 + 32 + 32 * qs + 8 * g];

  short8 ones;
#pragma unroll
  for (int i = 0; i < 8; ++i) ones[i] = (short)0x3F80;  // bf16 1.0

  f32x4 acc[4][2] = {};   // att 0,1,2 + 3 = shared (q5,k5); [att][n]
  f32x4 lsv[4] = {};      // row-sums, same row layout as acc

  int kk_key[3], kk_cc[3], vv_d[3], vv_c[3];
#pragma unroll
  for (int i = 0; i < 3; ++i) {
    int c = tid + i * 256;
    kk_key[i] = c / 12; kk_cc[i] = c % 12;
    vv_d[i] = c >> 3;   vv_c[i] = c & 7;
  }
  uint4 kst[3], vst[3];
#pragma unroll
  for (int i = 0; i < 3; ++i) {
    kst[i] = *(const uint4*)&qkv[(tb + kk_key[i]) * 2304 + 768 + h * 96 + kk_cc[i] * 8];
    vst[i] = *(const uint4*)&vt[((size_t)bh * 96 + vv_d[i]) * 1024 + vv_c[i] * 8];
  }

  const int ATT[5] = {0, 0, 1, 3, 2};
  const int QS[5]  = {0, 0, 1, 1, 1};
  const int KS[5]  = {0, 1, 0, 2, 1};

  for (int t = 0; t < 16; ++t) {
    __syncthreads();
#pragma unroll
    for (int i = 0; i < 3; ++i) {
      int part = kk_cc[i] >> 2, g4 = kk_cc[i] & 3;
      *(uint4*)&Kl[part * 2560 + kk_key[i] * 40 + g4 * 8] = kst[i];
      *(uint4*)&Vl[vv_d[i] * 72 + vv_c[i] * 8] = vst[i];
    }
    if (t < 15) {  // prefetch next tile into regs
      int kv0 = (t + 1) * 64;
#pragma unroll
      for (int i = 0; i < 3; ++i) {
        kst[i] = *(const uint4*)&qkv[(tb + kv0 + kk_key[i]) * 2304 + 768 + h * 96 + kk_cc[i] * 8];
        vst[i] = *(const uint4*)&vt[((size_t)bh * 96 + vv_d[i]) * 1024 + kv0 + vv_c[i] * 8];
      }
    }
    __syncthreads();

#pragma unroll
    for (int u = 0; u < 5; ++u) {
      const int att = ATT[u], qs = QS[u], ks = KS[u];
      short8 kf[4];
#pragma unroll
      for (int n = 0; n < 4; ++n)
        kf[n] = *(const short8*)&Kl[ks * 2560 + (n * 16 + c16) * 40 + g * 8];

      const f32x4 z = {0.f, 0.f, 0.f, 0.f};
      f32x4 St[4];
      __builtin_amdgcn_s_setprio(1);
#pragma unroll
      for (int n = 0; n < 4; ++n)
        St[n] = __builtin_amdgcn_mfma_f32_16x16x32_bf16(kf[n], qf[qs], z, 0, 0, 0);
      __builtin_amdgcn_s_setprio(0);
      short8 vf[2][2];
#pragma unroll
      for (int n = 0; n < 2; ++n)
#pragma unroll
        for (int kk = 0; kk < 2; ++kk)
          vf[n][kk] = *(const short8*)&Vl[(ks * 32 + n * 16 + c16) * 72 + kk * 32 + g * 8];
      short8 pa[2];
#pragma unroll
      for (int kk = 0; kk < 2; ++kk) {
        union { unsigned u[4]; short8 s; } w;
        w.u[0] = pkbf16(__builtin_amdgcn_exp2f(St[2 * kk][0]),     __builtin_amdgcn_exp2f(St[2 * kk][1]));
        w.u[1] = pkbf16(__builtin_amdgcn_exp2f(St[2 * kk][2]),     __builtin_amdgcn_exp2f(St[2 * kk][3]));
        w.u[2] = pkbf16(__builtin_amdgcn_exp2f(St[2 * kk + 1][0]), __builtin_amdgcn_exp2f(St[2 * kk + 1][1]));
        w.u[3] = pkbf16(__builtin_amdgcn_exp2f(St[2 * kk + 1][2]), __builtin_amdgcn_exp2f(St[2 * kk + 1][3]));
        pa[kk] = w.s;
      }
      __builtin_amdgcn_s_setprio(1);
#pragma unroll
      for (int n = 0; n < 2; ++n)
#pragma unroll
        for (int kk = 0; kk < 2; ++kk)
          acc[att][n] = __builtin_amdgcn_mfma_f32_16x16x32_bf16(pa[kk], vf[n][kk], acc[att][n], 0, 0, 0);
#pragma unroll
      for (int kk = 0; kk < 2; ++kk)
        lsv[att] = __builtin_amdgcn_mfma_f32_16x16x32_bf16(pa[kk], ones, lsv[att], 0, 0, 0);
      __builtin_amdgcn_s_setprio(0);
    }
  }

  // fold shared (q5,k5) block into x4 (att1) and x5 (att2)
  lsv[1] += lsv[3];
  lsv[2] += lsv[3];
#pragma unroll
  for (int n = 0; n < 2; ++n) {
    acc[1][n] += acc[3][n];
    acc[2][n] += acc[3][n];
  }

  // epilogue: stage per-wave 16x96 tile in LDS (overlay Kl), then coalesced stores
  __syncthreads();   // all waves done reading Kl/Vl
  u16* Ol = smem + wave * 1536;   // [16 rows][96 cols]
#pragma unroll
  for (int a = 0; a < 3; ++a) {
    f32x4 inv;
#pragma unroll
    for (int r = 0; r < 4; ++r) inv[r] = 1.0f / lsv[a][r];
#pragma unroll
    for (int n = 0; n < 2; ++n)
#pragma unroll
      for (int r = 0; r < 4; ++r)
        Ol[(g * 4 + r) * 96 + a * 32 + n * 16 + c16] = f2b(acc[a][n][r] * inv[r]);
  }
#pragma unroll
  for (int i = 0; i < 3; ++i) {
    int chunk = lane + 64 * i;          // 0..191
    int row = chunk / 12, cc = chunk % 12;
    uint4 val = *(const uint4*)&Ol[row * 96 + cc * 8];
    *(uint4*)&feat[(tb + q0 + row) * 768 + h * 96 + cc * 8] = val;
  }
}

// ---------------- launch ----------------
extern "C" void kernel_launch(void* const* d_in, const int* in_sizes, int n_in,
                              void* d_out, int out_size, void* d_ws, size_t ws_size,
                              hipStream_t stream) {
  const float* x  = (const float*)d_in[0];
  const float* wq = (const float*)d_in[1];
  const float* wp = (const float*)d_in[2];
  const float* bp = (const float*)d_in[3];
  float* out = (float*)d_out;

  char* ws = (char*)d_ws;
  u16* xb    = (u16*)(ws);                // 12,582,912 B  (reused as feat after GEMM1)
  u16* wqb   = (u16*)(ws + 12582912);     //  3,538,944 B
  u16* wpb   = (u16*)(ws + 16121856);     //  1,179,648 B
  u16* qkvb  = (u16*)(ws + 17301504);     // 37,748,736 B
  u16* vtb   = (u16*)(ws + 55050240);     // 12,582,912 B  (end: 67,633,152)
  u16* featb = xb;                        // xb is dead after GEMM1

  cvt3<<<8448, 256, 0, stream>>>(x, wq, wp, xb, wqb, wpb);
  gemm_bt<<<dim3(18, 64), 256, 0, stream>>>(xb, wqb, qkvb, nullptr, nullptr, 8192, 2304, 768);
  vtrans<<<1024, 256, 0, stream>>>(qkvb, vtb);
  attn_kernel<<<1024, 256, 0, stream>>>(qkvb, vtb, featb);
  gemm_bt<<<dim3(6, 64), 256, 0, stream>>>(featb, wpb, nullptr, out, bp, 8192, 768, 768);
}

// Round 5
// 167.065 us; speedup vs baseline: 1.2369x; 1.2369x over previous
//
#include <hip/hip_runtime.h>
#include <hip/hip_bf16.h>

typedef unsigned short u16;
typedef __attribute__((ext_vector_type(8))) short short8;
typedef __attribute__((ext_vector_type(4))) float f32x4;
typedef __attribute__((ext_vector_type(4))) unsigned uint32x4;

__device__ __forceinline__ u16 f2b(float f) {
  unsigned u = __builtin_bit_cast(unsigned, f);
  unsigned r = u + 0x7fffu + ((u >> 16) & 1u);   // RNE bf16 (finite inputs)
  return (u16)(r >> 16);
}

__device__ __forceinline__ unsigned pkbf16(float lo, float hi) {
  unsigned r;
  asm("v_cvt_pk_bf16_f32 %0, %1, %2" : "=v"(r) : "v"(lo), "v"(hi));
  return r;
}

#define GLD_LDS16(gp, lp) __builtin_amdgcn_global_load_lds( \
    (const __attribute__((address_space(1))) void*)(gp),    \
    (__attribute__((address_space(3))) void*)(lp), 16, 0, 0)

// ---------------- fp32 -> bf16 convert ----------------
// Q-rows of w_qkv pre-scaled by scale*log2e; w_proj K-columns permuted
// i = a*256 + h*32 + c  ->  i' = h*96 + a*32 + c  (matches attn's feat layout).
__global__ __launch_bounds__(256) void cvt3(
    const float* __restrict__ x, const float* __restrict__ wq, const float* __restrict__ wp,
    u16* __restrict__ xb, u16* __restrict__ wqb, u16* __restrict__ wpb)
{
  const int NX = 8192 * 768 / 4, NQ = 2304 * 768 / 4, NP = 768 * 768 / 4;
  int i = blockIdx.x * 256 + threadIdx.x;
  if (i < NX) {
    float4 v = *(const float4*)&x[(size_t)i * 4];
    u16 o0 = f2b(v.x), o1 = f2b(v.y), o2 = f2b(v.z), o3 = f2b(v.w);
    unsigned lo = (unsigned)o0 | ((unsigned)o1 << 16);
    unsigned hi = (unsigned)o2 | ((unsigned)o3 << 16);
    uint2 pk; pk.x = lo; pk.y = hi;
    *(uint2*)&xb[(size_t)i * 4] = pk;
  } else if (i < NX + NQ) {
    int j = i - NX;
    float sc = (j < 147456) ? 0.14724447f : 1.0f;   // rows 0..767 (Q) * scale*log2e
    float4 v = *(const float4*)&wq[(size_t)j * 4];
    u16 o0 = f2b(v.x * sc), o1 = f2b(v.y * sc), o2 = f2b(v.z * sc), o3 = f2b(v.w * sc);
    uint2 pk; pk.x = (unsigned)o0 | ((unsigned)o1 << 16); pk.y = (unsigned)o2 | ((unsigned)o3 << 16);
    *(uint2*)&wqb[(size_t)j * 4] = pk;
  } else if (i < NX + NQ + NP) {
    int j = i - NX - NQ;
    int oo = (j * 4) / 768, ii = (j * 4) % 768;
    int a = ii >> 8, h = (ii >> 5) & 7, c = ii & 31;
    float4 v = *(const float4*)&wp[(size_t)j * 4];
    u16 o0 = f2b(v.x), o1 = f2b(v.y), o2 = f2b(v.z), o3 = f2b(v.w);
    uint2 pk; pk.x = (unsigned)o0 | ((unsigned)o1 << 16); pk.y = (unsigned)o2 | ((unsigned)o3 << 16);
    *(uint2*)&wpb[oo * 768 + h * 96 + a * 32 + c] = pk;
  }
}

// ---------------- 128x128 bf16 GEMM, C = A @ Bt^T (both K-contiguous) ----------------
__global__ __launch_bounds__(256) void gemm_bt(
    const u16* __restrict__ A, const u16* __restrict__ Bt,
    u16* __restrict__ Cb, float* __restrict__ Cf, const float* __restrict__ bias,
    int M, int N, int K)
{
  __shared__ u16 Al[128 * 32];
  __shared__ u16 Bl[128 * 32];
  const int tid = threadIdx.x;
  const int lane = tid & 63, wave = tid >> 6;
  const int wr = wave >> 1, wc = wave & 1;
  const int g = lane >> 4, c16 = lane & 15;
  const int m0 = blockIdx.y * 128, n0 = blockIdx.x * 128;

  f32x4 acc[4][4] = {};

  const int c0 = tid, c1 = tid + 256;
  const int r0 = c0 >> 2, o0 = (c0 & 3) * 8;
  const int r1 = c1 >> 2, o1 = (c1 & 3) * 8;
  const u16* a0 = A + (size_t)(m0 + r0) * K + o0;
  const u16* a1 = A + (size_t)(m0 + r1) * K + o1;
  const u16* b0 = Bt + (size_t)(n0 + r0) * K + o0;
  const u16* b1 = Bt + (size_t)(n0 + r1) * K + o1;

  for (int k0 = 0; k0 < K; k0 += 32) {
    GLD_LDS16(a0 + k0, Al + c0 * 8);
    GLD_LDS16(a1 + k0, Al + c1 * 8);
    GLD_LDS16(b0 + k0, Bl + c0 * 8);
    GLD_LDS16(b1 + k0, Bl + c1 * 8);
    __syncthreads();
    short8 af[4], bfr[4];
#pragma unroll
    for (int m = 0; m < 4; ++m)
      af[m] = *(const short8*)&Al[(wr * 64 + m * 16 + c16) * 32 + g * 8];
#pragma unroll
    for (int n = 0; n < 4; ++n)
      bfr[n] = *(const short8*)&Bl[(wc * 64 + n * 16 + c16) * 32 + g * 8];
#pragma unroll
    for (int m = 0; m < 4; ++m)
#pragma unroll
      for (int n = 0; n < 4; ++n)
        acc[m][n] = __builtin_amdgcn_mfma_f32_16x16x32_bf16(af[m], bfr[n], acc[m][n], 0, 0, 0);
    __syncthreads();
  }

  if (Cb) {
#pragma unroll
    for (int m = 0; m < 4; ++m) {
      const int row = m0 + wr * 64 + m * 16 + g * 4;
#pragma unroll
      for (int n = 0; n < 4; ++n) {
        const int col = n0 + wc * 64 + n * 16 + c16;
#pragma unroll
        for (int j = 0; j < 4; ++j)
          Cb[(size_t)(row + j) * N + col] = f2b(acc[m][n][j]);
      }
    }
  } else {
#pragma unroll
    for (int m = 0; m < 4; ++m) {
      const int row = m0 + wr * 64 + m * 16 + g * 4;
#pragma unroll
      for (int n = 0; n < 4; ++n) {
        const int col = n0 + wc * 64 + n * 16 + c16;
        const float bb = bias[col];
#pragma unroll
        for (int j = 0; j < 4; ++j)
          Cf[(size_t)(row + j) * N + col] = acc[m][n][j] + bb;
      }
    }
  }
}

// ---------------- V transpose (key-permuted): vt[bh][d][n] ----------------
// Within each 32-key chunk, key o=16*np+4*gp+r stored at slot 8*gp+4*np+r so the
// PV B-fragment's instruction-k order matches the in-register P packing.
__global__ __launch_bounds__(256) void vtrans(const u16* __restrict__ qkv, u16* __restrict__ vt)
{
  __shared__ u16 Vtl[96 * 72];
  const int tid = threadIdx.x;
  const int bh = blockIdx.x >> 4, nt = blockIdx.x & 15;
  const int b = bh >> 3, h = bh & 7;
  const int n0 = nt * 64;
  const size_t tb = (size_t)b * 1024;
#pragma unroll
  for (int i = 0; i < 3; ++i) {
    int c = tid + i * 256;
    int key = c / 12, cc = c % 12;
    short8 v = *(const short8*)&qkv[(tb + n0 + key) * 2304 + 1536 + h * 96 + cc * 8];
#pragma unroll
    for (int j = 0; j < 8; ++j)
      Vtl[(cc * 8 + j) * 72 + key] = (u16)v[j];
  }
  __syncthreads();
#pragma unroll
  for (int i = 0; i < 3; ++i) {
    int c = tid + i * 256;
    int d = c >> 3, c2 = c & 7;
    int chunk = c2 >> 2;
    int kA = ((c2 & 1) << 4) | ((c2 & 2) << 1);   // c2&3 = 0,1,2,3 -> 0,16,4,20
    const u16* src = &Vtl[d * 72 + c2 * 8];
    size_t base = ((size_t)bh * 96 + d) * 1024 + n0 + chunk * 32;
    *(uint2*)&vt[base + kA]     = *(const uint2*)(src);
    *(uint2*)&vt[base + kA + 8] = *(const uint2*)(src + 4);
  }
}

// ---------------- tri-attention: 32 q/wave, in-register P, ones-MFMA rowsum ----------------
// 1-D grid 512: id = h + 8*qt + 64*b -> all q-tiles of one batch on one XCD.
// S^T = mfma(K,Q) (Q pre-scaled by c2s); P = exp2 in-register -> cvt_pk ->
// bit_cast (NO unions: keeps everything in VGPRs, no scratch) -> PV.
// Row-sum via mfma(pa, ones). (q5,k5) block shared by x4/x5 (att=3).
// Epilogue: per-wave LDS-staged transpose -> 16B coalesced feat stores in
// permuted layout col' = h*96 + a*32 + c (w_proj permuted to match).
__global__ __launch_bounds__(256, 2) void attn_kernel(
    const u16* __restrict__ qkv, const u16* __restrict__ vt, u16* __restrict__ feat)
{
  __shared__ u16 smem[3 * 64 * 40 + 96 * 72];   // Kl(3x64x40) | Vl(96x72) = 29184 B
  u16* Kl = smem;                // [ks][key][32d], row stride 40 (+8 pad)
  u16* Vl = smem + 3 * 64 * 40;  // [d][64 key-slots], row stride 72 (+8 pad)

  const int tid = threadIdx.x;
  const int lane = tid & 63, wave = tid >> 6;
  const int g = lane >> 4, c16 = lane & 15;
  const int id = blockIdx.x;
  const int h = id & 7, qt = (id >> 3) & 7, b = id >> 6;
  const int bh = b * 8 + h;
  const int q0 = qt * 128 + wave * 32;
  const size_t tb = (size_t)b * 1024;

  short8 qf[2][2];
#pragma unroll
  for (int qs = 0; qs < 2; ++qs)
#pragma unroll
    for (int m = 0; m < 2; ++m)
      qf[qs][m] = *(const short8*)&qkv[(tb + q0 + m * 16 + c16) * 2304 + h * 96 + 32 + 32 * qs + 8 * g];

  short8 ones;
#pragma unroll
  for (int i = 0; i < 8; ++i) ones[i] = (short)0x3F80;  // bf16 1.0

  f32x4 acc[4][2][2] = {};   // [att][m][n]; att 3 = shared (q5,k5)
  f32x4 lsv[4][2] = {};      // row-sums, same row layout as acc

  int kk_key[3], kk_cc[3], vv_d[3], vv_c[3];
#pragma unroll
  for (int i = 0; i < 3; ++i) {
    int c = tid + i * 256;
    kk_key[i] = c / 12; kk_cc[i] = c % 12;
    vv_d[i] = c >> 3;   vv_c[i] = c & 7;
  }
  uint4 kst[3], vst[3];
#pragma unroll
  for (int i = 0; i < 3; ++i) {
    kst[i] = *(const uint4*)&qkv[(tb + kk_key[i]) * 2304 + 768 + h * 96 + kk_cc[i] * 8];
    vst[i] = *(const uint4*)&vt[((size_t)bh * 96 + vv_d[i]) * 1024 + vv_c[i] * 8];
  }

  const int ATT[5] = {0, 0, 1, 3, 2};
  const int QS[5]  = {0, 0, 1, 1, 1};
  const int KS[5]  = {0, 1, 0, 2, 1};

  for (int t = 0; t < 16; ++t) {
    __syncthreads();
#pragma unroll
    for (int i = 0; i < 3; ++i) {
      int part = kk_cc[i] >> 2, g4 = kk_cc[i] & 3;
      *(uint4*)&Kl[part * 2560 + kk_key[i] * 40 + g4 * 8] = kst[i];
      *(uint4*)&Vl[vv_d[i] * 72 + vv_c[i] * 8] = vst[i];
    }
    if (t < 15) {  // prefetch next tile into regs
      int kv0 = (t + 1) * 64;
#pragma unroll
      for (int i = 0; i < 3; ++i) {
        kst[i] = *(const uint4*)&qkv[(tb + kv0 + kk_key[i]) * 2304 + 768 + h * 96 + kk_cc[i] * 8];
        vst[i] = *(const uint4*)&vt[((size_t)bh * 96 + vv_d[i]) * 1024 + kv0 + vv_c[i] * 8];
      }
    }
    __syncthreads();

#pragma unroll
    for (int u = 0; u < 5; ++u) {
      const int att = ATT[u], qs = QS[u], ks = KS[u];
      short8 kf[4], vf[2][2];
#pragma unroll
      for (int n = 0; n < 4; ++n)
        kf[n] = *(const short8*)&Kl[ks * 2560 + (n * 16 + c16) * 40 + g * 8];
#pragma unroll
      for (int n = 0; n < 2; ++n)
#pragma unroll
        for (int kk = 0; kk < 2; ++kk)
          vf[n][kk] = *(const short8*)&Vl[(ks * 32 + n * 16 + c16) * 72 + kk * 32 + g * 8];

      const f32x4 z = {0.f, 0.f, 0.f, 0.f};
#pragma unroll
      for (int m = 0; m < 2; ++m) {
        f32x4 St[4];
        __builtin_amdgcn_s_setprio(1);
#pragma unroll
        for (int n = 0; n < 4; ++n)
          St[n] = __builtin_amdgcn_mfma_f32_16x16x32_bf16(kf[n], qf[qs][m], z, 0, 0, 0);
        __builtin_amdgcn_s_setprio(0);
        short8 pa[2];
#pragma unroll
        for (int kk = 0; kk < 2; ++kk) {
          uint32x4 w;
          w.x = pkbf16(__builtin_amdgcn_exp2f(St[2 * kk][0]),     __builtin_amdgcn_exp2f(St[2 * kk][1]));
          w.y = pkbf16(__builtin_amdgcn_exp2f(St[2 * kk][2]),     __builtin_amdgcn_exp2f(St[2 * kk][3]));
          w.z = pkbf16(__builtin_amdgcn_exp2f(St[2 * kk + 1][0]), __builtin_amdgcn_exp2f(St[2 * kk + 1][1]));
          w.w = pkbf16(__builtin_amdgcn_exp2f(St[2 * kk + 1][2]), __builtin_amdgcn_exp2f(St[2 * kk + 1][3]));
          pa[kk] = __builtin_bit_cast(short8, w);
        }
        __builtin_amdgcn_s_setprio(1);
#pragma unroll
        for (int n = 0; n < 2; ++n)
#pragma unroll
          for (int kk = 0; kk < 2; ++kk)
            acc[att][m][n] = __builtin_amdgcn_mfma_f32_16x16x32_bf16(pa[kk], vf[n][kk], acc[att][m][n], 0, 0, 0);
#pragma unroll
        for (int kk = 0; kk < 2; ++kk)
          lsv[att][m] = __builtin_amdgcn_mfma_f32_16x16x32_bf16(pa[kk], ones, lsv[att][m], 0, 0, 0);
        __builtin_amdgcn_s_setprio(0);
      }
    }
  }

  // fold shared (q5,k5) block into x4 (att1) and x5 (att2)
#pragma unroll
  for (int m = 0; m < 2; ++m) {
    lsv[1][m] += lsv[3][m];
    lsv[2][m] += lsv[3][m];
#pragma unroll
    for (int n = 0; n < 2; ++n) {
      acc[1][m][n] += acc[3][m][n];
      acc[2][m][n] += acc[3][m][n];
    }
  }

  // epilogue: stage per-wave 32x96 tile in LDS (overlay Kl/Vl), coalesced stores
  __syncthreads();   // all waves done reading Kl/Vl
  u16* Ol = smem + wave * 3072;   // [32 rows][96 cols]
#pragma unroll
  for (int a = 0; a < 3; ++a)
#pragma unroll
    for (int m = 0; m < 2; ++m) {
      f32x4 inv;
#pragma unroll
      for (int r = 0; r < 4; ++r) inv[r] = 1.0f / lsv[a][m][r];
#pragma unroll
      for (int n = 0; n < 2; ++n)
#pragma unroll
        for (int r = 0; r < 4; ++r)
          Ol[(m * 16 + g * 4 + r) * 96 + a * 32 + n * 16 + c16] = f2b(acc[a][m][n][r] * inv[r]);
    }
  __builtin_amdgcn_s_barrier();  // wave-local ordering not enough? ds_write->ds_read same wave is ordered by lgkmcnt; keep barrier out
#pragma unroll
  for (int i = 0; i < 6; ++i) {
    int chunk = lane + 64 * i;          // 0..383
    int row = chunk / 12, cc = chunk % 12;
    uint4 val = *(const uint4*)&Ol[row * 96 + cc * 8];
    *(uint4*)&feat[(tb + q0 + row) * 768 + h * 96 + cc * 8] = val;
  }
}

// ---------------- launch ----------------
extern "C" void kernel_launch(void* const* d_in, const int* in_sizes, int n_in,
                              void* d_out, int out_size, void* d_ws, size_t ws_size,
                              hipStream_t stream) {
  const float* x  = (const float*)d_in[0];
  const float* wq = (const float*)d_in[1];
  const float* wp = (const float*)d_in[2];
  const float* bp = (const float*)d_in[3];
  float* out = (float*)d_out;

  char* ws = (char*)d_ws;
  u16* xb    = (u16*)(ws);                // 12,582,912 B  (reused as feat after GEMM1)
  u16* wqb   = (u16*)(ws + 12582912);     //  3,538,944 B
  u16* wpb   = (u16*)(ws + 16121856);     //  1,179,648 B
  u16* qkvb  = (u16*)(ws + 17301504);     // 37,748,736 B
  u16* vtb   = (u16*)(ws + 55050240);     // 12,582,912 B  (end: 67,633,152)
  u16* featb = xb;                        // xb is dead after GEMM1

  cvt3<<<8448, 256, 0, stream>>>(x, wq, wp, xb, wqb, wpb);
  gemm_bt<<<dim3(18, 64), 256, 0, stream>>>(xb, wqb, qkvb, nullptr, nullptr, 8192, 2304, 768);
  vtrans<<<1024, 256, 0, stream>>>(qkvb, vtb);
  attn_kernel<<<512, 256, 0, stream>>>(qkvb, vtb, featb);
  gemm_bt<<<dim3(6, 64), 256, 0, stream>>>(featb, wpb, nullptr, out, bp, 8192, 768, 768);
}